// Round 3
// baseline (29.694 us; speedup 1.0000x reference)
//
#include <hip/hip_runtime.h>
#include <math.h>

// TripletCenterLoss, collapsed O(B^2) -> O(B*C):
//   dist_ap[i] = ||x_i - centers[t_i]||    (all same-class j share it; j=i exists)
//   dist_an[i] = min_{c present, c != t_i} ||x_i - centers[c]||
//   loss = mean(relu(MARGIN + dist_ap - dist_an))
// d2 via x2 + c2 - 2*x.c (reference's own expansion), dist = sqrt(clip(d2,1e-12)).
//
// Geometry: 256 blocks x 256 threads (1 block/CU), 32 rows/block.
// Each WAVE owns 8 rows; lane l owns classes {2l, 2l+1} (CPAD=128, 100 real).
// One center ds_read_b128 feeds 8 rows' FMAs (R=8 reuse) -> LDS ~1.3us/CU,
// VALU ~1.8us/CU is the cap. x-row chunks are wave-uniform: one vaddr,
// immediate offsets. Center LDS layout XOR-swizzled so the stride-1024B
// per-lane reads are conflict-free: byte = cl*512 + 16*(d4 ^ (lane&7))
// -> (addr/16)%8 == d4 ^ (lane&7), a per-cycle bank permutation.
// Final mean fused via arrival counter in d_ws (zeroed by a memset node).

constexpr int T = 256;
constexpr int RPB = 32;        // rows per block
constexpr int RPW = 8;         // rows per wave
constexpr int CPAD = 128;      // padded classes (2 per lane)
constexpr int C = 100;
constexpr float MARGIN = 5.0f;

__device__ __forceinline__ float4 fma4(float4 a, float4 b, float4 c) {
    return make_float4(fmaf(a.x, b.x, c.x), fmaf(a.y, b.y, c.y),
                       fmaf(a.z, b.z, c.z), fmaf(a.w, b.w, c.w));
}
__device__ __forceinline__ float hsum4(float4 v) {
    return (v.x + v.y) + (v.z + v.w);
}

__global__ __launch_bounds__(256) void tcl_fused(
    const float* __restrict__ x, const int* __restrict__ tgt,
    const float* __restrict__ cen, int* __restrict__ cnt,
    float* __restrict__ partial, float* __restrict__ out,
    int B, int nblocks, float invB)
{
    __shared__ float4 ldsC4[CPAD * 32];      // 64 KB, swizzled centers
    __shared__ float c2s[CPAD];
    __shared__ float x2s[RPB];
    __shared__ unsigned char present[CPAD];
    __shared__ float wred[4];
    __shared__ int lastFlag;

    const int tid = threadIdx.x;
    const int bid = blockIdx.x;
    const char* ldsB = (const char*)ldsC4;

    // ---- phase 1: stage centers swizzled (zero-pad cl>=100), clear present ----
    #pragma unroll
    for (int k = 0; k < 16; ++k) {
        const int i = k * T + tid;            // i == cl*32 + d4 == linear src chunk
        const int cl = i >> 5, d4 = i & 31;
        float4 v = make_float4(0.f, 0.f, 0.f, 0.f);
        if (cl < C) v = reinterpret_cast<const float4*>(cen)[i];
        const int off = cl * 512 + ((d4 ^ ((cl >> 1) & 7)) << 4);  // bytes
        *reinterpret_cast<float4*>(const_cast<char*>(ldsB) + off) = v;
    }
    if (tid < CPAD) present[tid] = 0;
    __syncthreads();

    // ---- phase 2 (split across waves): c2 | presence | x2 ----
    if (tid < C) {
        const int vb = tid * 512 + (((tid >> 1) & 7) << 4);
        float4 acc = make_float4(0.f, 0.f, 0.f, 0.f);
        #pragma unroll 8
        for (int d4 = 0; d4 < 32; ++d4) {
            const float4 v = *reinterpret_cast<const float4*>(ldsB + (vb ^ (d4 << 4)));
            acc = fma4(v, v, acc);
        }
        c2s[tid] = hsum4(acc);
    } else if (tid < CPAD) {
        c2s[tid] = 0.f;                        // pad classes excluded via present[]
    } else if (tid < 192) {
        for (int idx = tid - 128; idx < (B >> 2); idx += 64) {
            const int4 tv = reinterpret_cast<const int4*>(tgt)[idx];
            present[tv.x] = 1; present[tv.y] = 1;
            present[tv.z] = 1; present[tv.w] = 1;
        }
    } else {
        const int i = tid - 192, row = i >> 1, h = i & 1;
        const float4* xr = reinterpret_cast<const float4*>(
            x + (size_t)(bid * RPB + row) * 128);
        float4 acc = make_float4(0.f, 0.f, 0.f, 0.f);
        #pragma unroll
        for (int d4 = h * 16; d4 < h * 16 + 16; ++d4) acc = fma4(xr[d4], xr[d4], acc);
        float s = hsum4(acc);
        s += __shfl_xor(s, 1);
        if (h == 0) x2s[row] = s;
    }
    __syncthreads();

    // ---- main loop: 8 rows/wave, 2 classes/lane ----
    const int lane = tid & 63;
    const int wid  = __builtin_amdgcn_readfirstlane(tid >> 6);
    const int rowb = bid * RPB + wid * RPW;
    const float* xb = x + (size_t)rowb * 128;          // wave-uniform base
    const int vb = lane * 1024 + ((lane & 7) << 4);    // swizzled lane base (bytes)

    float4 a[RPW][2];
    #pragma unroll
    for (int r = 0; r < RPW; ++r) {
        a[r][0] = make_float4(0.f, 0.f, 0.f, 0.f);
        a[r][1] = make_float4(0.f, 0.f, 0.f, 0.f);
    }

    #pragma unroll 4
    for (int d4 = 0; d4 < 32; ++d4) {
        float4 xv[RPW];
        #pragma unroll
        for (int r = 0; r < RPW; ++r)
            xv[r] = *reinterpret_cast<const float4*>(xb + r * 128 + d4 * 4);
        const char* p = ldsB + (vb ^ (d4 << 4));
        const float4 cv0 = *reinterpret_cast<const float4*>(p);
        const float4 cv1 = *reinterpret_cast<const float4*>(p + 512);
        #pragma unroll
        for (int r = 0; r < RPW; ++r) {
            a[r][0] = fma4(xv[r], cv0, a[r][0]);
            a[r][1] = fma4(xv[r], cv1, a[r][1]);
        }
    }

    // ---- epilogue: d2, ap/an per row, 64-lane butterfly, per-wave term sum ----
    int tr[RPW]; float x2v[RPW];
    #pragma unroll
    for (int r = 0; r < RPW; ++r) {
        tr[r]  = tgt[rowb + r];
        x2v[r] = x2s[wid * RPW + r];
    }
    const int cl0 = 2 * lane, cl1 = 2 * lane + 1;
    const float c20 = c2s[cl0], c21 = c2s[cl1];
    const bool p0 = present[cl0] != 0, p1 = present[cl1] != 0;

    float term = 0.f;
    #pragma unroll
    for (int r = 0; r < RPW; ++r) {
        const float d20 = fmaxf(x2v[r] + c20 - 2.f * hsum4(a[r][0]), 1e-12f);
        const float d21 = fmaxf(x2v[r] + c21 - 2.f * hsum4(a[r][1]), 1e-12f);
        float ap = (cl0 == tr[r]) ? d20 : ((cl1 == tr[r]) ? d21 : -1.f);
        float an = fminf((p0 && cl0 != tr[r]) ? d20 : INFINITY,
                         (p1 && cl1 != tr[r]) ? d21 : INFINITY);
        #pragma unroll
        for (int off = 1; off < 64; off <<= 1) {
            ap = fmaxf(ap, __shfl_xor(ap, off));
            an = fminf(an, __shfl_xor(an, off));
        }
        term += fmaxf(0.f, MARGIN + sqrtf(ap) - sqrtf(an));
    }

    if ((tid & 63) == 0) wred[wid] = term;
    __syncthreads();
    if (tid == 0) {
        partial[bid] = (wred[0] + wred[1]) + (wred[2] + wred[3]);
        __threadfence();                               // release partial[bid]
        lastFlag = (atomicAdd(cnt, 1) == nblocks - 1);
    }
    __syncthreads();

    // ---- last arriving block: deterministic final sum ----
    if (lastFlag) {
        __threadfence();                               // acquire all partials
        float v = (tid < nblocks) ? partial[tid] : 0.f;
        #pragma unroll
        for (int off = 1; off < 64; off <<= 1) v += __shfl_xor(v, off);
        if ((tid & 63) == 0) wred[tid >> 6] = v;
        __syncthreads();
        if (tid == 0)
            out[0] = ((wred[0] + wred[1]) + (wred[2] + wred[3])) * invB;
    }
}

extern "C" void kernel_launch(void* const* d_in, const int* in_sizes, int n_in,
                              void* d_out, int out_size, void* d_ws, size_t ws_size,
                              hipStream_t stream)
{
    const float* x   = (const float*)d_in[0];   // [B, 128] f32
    const int*   tgt = (const int*)d_in[1];     // [B] int32 (harness-converted)
    const float* cen = (const float*)d_in[2];   // [100, 128] f32
    float* out = (float*)d_out;                 // scalar f32

    const int B = in_sizes[1];                  // 8192
    const int nblocks = B / RPB;                // 256

    int*   cnt     = (int*)d_ws;
    float* partial = (float*)((char*)d_ws + 256);

    hipMemsetAsync(d_ws, 0, 4, stream);         // zero arrival counter (graph-safe)
    tcl_fused<<<nblocks, T, 0, stream>>>(x, tgt, cen, cnt, partial, out,
                                         B, nblocks, 1.0f / (float)B);
}

// Round 4
// 21.875 us; speedup vs baseline: 1.3575x; 1.3575x over previous
//
#include <hip/hip_runtime.h>
#include <math.h>

// TripletCenterLoss, collapsed O(B^2) -> O(B*C):
//   dist_ap[i] = ||x_i - centers[t_i]||    (all same-class j share it; j=i exists)
//   dist_an[i] = min_{c present, c != t_i} ||x_i - centers[c]||
//   loss = mean(relu(MARGIN + dist_ap - dist_an))
// d2 via x2 + c2 - 2*x.c (reference's own expansion), dist = sqrt(clip(d2,1e-12)).
//
// Geometry: 256 blocks x 256 threads (1 block/CU), 32 rows/block.
// Each WAVE owns 8 rows; lane l owns classes {2l, 2l+1} (CPAD=128, pads alias
// class 0 and are masked via present[]). One center ds_read_b128 feeds 8 rows'
// FMAs -> LDS ~256 insts/CU (~1.3us), VALU ~1.7us is the cap. x-row chunks are
// wave-uniform (scalar-loadable). Center LDS XOR-swizzled:
//   byte(cl,d4) = cl*512 + ((d4 ^ ((cl>>1)&7))<<4)
// -> main-loop reads are a per-cycle bank permutation of the canonical
// conflict-free linear pattern. Staged via global_load_lds (linear LDS dest,
// pre-swizzled per-lane GLOBAL source - m173 pattern).
// NOTE (round-3 lesson): a 4-byte hipMemsetAsync graph node costs ~11us
// (shows as a 40us fillBufferAligned dispatch) - two kernels beat memset+fused.

constexpr int T = 256;
constexpr int RPB = 32;        // rows per block
constexpr int RPW = 8;         // rows per wave
constexpr int CPAD = 128;      // padded classes (2 per lane)
constexpr int C = 100;
constexpr float MARGIN = 5.0f;

__device__ __forceinline__ float4 fma4(float4 a, float4 b, float4 c) {
    return make_float4(fmaf(a.x, b.x, c.x), fmaf(a.y, b.y, c.y),
                       fmaf(a.z, b.z, c.z), fmaf(a.w, b.w, c.w));
}
__device__ __forceinline__ float hsum4(float4 v) {
    return (v.x + v.y) + (v.z + v.w);
}

__global__ __launch_bounds__(256) void tcl_main(
    const float* __restrict__ x, const int* __restrict__ tgt,
    const float* __restrict__ cen, float* __restrict__ partial, int B)
{
    __shared__ float4 ldsC4[CPAD * 32];      // 64 KB, swizzled centers
    __shared__ float c2s[CPAD];
    __shared__ float x2s[RPB];
    __shared__ unsigned char present[CPAD];
    __shared__ float wred[4];

    const int tid  = threadIdx.x;
    const int bid  = blockIdx.x;
    const int lane = tid & 63;
    const int wid  = __builtin_amdgcn_readfirstlane(tid >> 6);
    char* ldsB = (char*)ldsC4;

    // ---- phase 1: async-stage centers. Linear LDS dest (wave base + lane*16),
    // per-lane pre-swizzled global source => swizzled layout lands in LDS. ----
    #pragma unroll
    for (int k = 0; k < 16; ++k) {
        const int j  = k * 256 + tid;                 // linear dest chunk 0..4095
        const int cl = j >> 5;
        const int scl = (cl < C) ? cl : 0;            // pads alias class 0 (masked)
        const int srcChunk = scl * 32 + ((j & 31) ^ ((scl >> 1) & 7));
        __builtin_amdgcn_global_load_lds(
            (const __attribute__((address_space(1))) void*)
                ((const char*)cen + (size_t)srcChunk * 16),
            (__attribute__((address_space(3))) void*)(ldsB + (k * 4 + wid) * 1024),
            16, 0, 0);
    }
    if (tid < CPAD) present[tid] = 0;
    __syncthreads();   // barrier drains vmcnt(0) -> staging complete

    // ---- phase 2 (one wave each): c2 from LDS | presence | x2 ----
    if (tid < CPAD) {
        // c2 for all 128 rows (pads get class-0's value; never used).
        const int vbb = tid * 512 + (((tid >> 1) & 7) << 4);
        float4 acc = make_float4(0.f, 0.f, 0.f, 0.f);
        #pragma unroll 8
        for (int e = 0; e < 32; ++e) {
            const float4 v = *reinterpret_cast<const float4*>(ldsB + (vbb ^ (e << 4)));
            acc = fma4(v, v, acc);
        }
        c2s[tid] = hsum4(acc);
    } else if (tid < 192) {
        for (int idx = tid - 128; idx < (B >> 2); idx += 64) {
            const int4 tv = reinterpret_cast<const int4*>(tgt)[idx];
            present[tv.x] = 1; present[tv.y] = 1;
            present[tv.z] = 1; present[tv.w] = 1;
        }
    } else {
        const int i = tid - 192, row = i >> 1, h = i & 1;
        const float4* xr = reinterpret_cast<const float4*>(
            x + (size_t)(bid * RPB + row) * 128);
        float4 acc = make_float4(0.f, 0.f, 0.f, 0.f);
        #pragma unroll
        for (int d4 = h * 16; d4 < h * 16 + 16; ++d4) acc = fma4(xr[d4], xr[d4], acc);
        float s = hsum4(acc);
        s += __shfl_xor(s, 1);
        if (h == 0) x2s[row] = s;
    }
    __syncthreads();

    // ---- main loop: 8 rows/wave, 2 classes/lane ----
    const int rowb = bid * RPB + wid * RPW;
    const float* xb = x + (size_t)rowb * 128;          // wave-uniform base
    const int vb = lane * 1024 + ((lane & 7) << 4);    // swizzled lane base (bytes)

    float4 a[RPW][2];
    #pragma unroll
    for (int r = 0; r < RPW; ++r) {
        a[r][0] = make_float4(0.f, 0.f, 0.f, 0.f);
        a[r][1] = make_float4(0.f, 0.f, 0.f, 0.f);
    }

    #pragma unroll 4
    for (int d4 = 0; d4 < 32; ++d4) {
        float4 xv[RPW];
        #pragma unroll
        for (int r = 0; r < RPW; ++r)
            xv[r] = *reinterpret_cast<const float4*>(xb + r * 128 + d4 * 4);
        const char* p = ldsB + (vb ^ (d4 << 4));
        const float4 cv0 = *reinterpret_cast<const float4*>(p);
        const float4 cv1 = *reinterpret_cast<const float4*>(p + 512);
        #pragma unroll
        for (int r = 0; r < RPW; ++r) {
            a[r][0] = fma4(xv[r], cv0, a[r][0]);
            a[r][1] = fma4(xv[r], cv1, a[r][1]);
        }
    }

    // ---- epilogue: d2, ap/an per row, 64-lane butterfly, per-wave term sum ----
    int tr[RPW]; float x2v[RPW];
    #pragma unroll
    for (int r = 0; r < RPW; ++r) {
        tr[r]  = tgt[rowb + r];                        // wave-uniform scalar loads
        x2v[r] = x2s[wid * RPW + r];
    }
    const int cl0 = 2 * lane, cl1 = 2 * lane + 1;
    const float c20 = c2s[cl0], c21 = c2s[cl1];
    const bool p0 = present[cl0] != 0, p1 = present[cl1] != 0;

    float term = 0.f;
    #pragma unroll
    for (int r = 0; r < RPW; ++r) {
        const float d20 = fmaxf(x2v[r] + c20 - 2.f * hsum4(a[r][0]), 1e-12f);
        const float d21 = fmaxf(x2v[r] + c21 - 2.f * hsum4(a[r][1]), 1e-12f);
        float ap = (cl0 == tr[r]) ? d20 : ((cl1 == tr[r]) ? d21 : -1.f);
        float an = fminf((p0 && cl0 != tr[r]) ? d20 : INFINITY,
                         (p1 && cl1 != tr[r]) ? d21 : INFINITY);
        #pragma unroll
        for (int off = 1; off < 64; off <<= 1) {
            ap = fmaxf(ap, __shfl_xor(ap, off));
            an = fminf(an, __shfl_xor(an, off));
        }
        term += fmaxf(0.f, MARGIN + sqrtf(ap) - sqrtf(an));
    }

    if (lane == 0) wred[wid] = term;
    __syncthreads();
    if (tid == 0) partial[bid] = (wred[0] + wred[1]) + (wred[2] + wred[3]);
}

__global__ __launch_bounds__(256) void tcl_reduce(
    const float* __restrict__ partial, float* __restrict__ out,
    int n, float invB)
{
    __shared__ float wred[4];
    const int tid = threadIdx.x;
    float v = (tid < n) ? partial[tid] : 0.0f;
    #pragma unroll
    for (int off = 1; off < 64; off <<= 1) v += __shfl_xor(v, off);
    if ((tid & 63) == 0) wred[tid >> 6] = v;
    __syncthreads();
    if (tid == 0)
        out[0] = ((wred[0] + wred[1]) + (wred[2] + wred[3])) * invB;
}

extern "C" void kernel_launch(void* const* d_in, const int* in_sizes, int n_in,
                              void* d_out, int out_size, void* d_ws, size_t ws_size,
                              hipStream_t stream)
{
    const float* x   = (const float*)d_in[0];   // [B, 128] f32
    const int*   tgt = (const int*)d_in[1];     // [B] int32 (harness-converted)
    const float* cen = (const float*)d_in[2];   // [100, 128] f32
    float* out = (float*)d_out;                 // scalar f32
    float* partial = (float*)d_ws;

    const int B = in_sizes[1];                  // 8192
    const int nblocks = B / RPB;                // 256

    tcl_main<<<nblocks, T, 0, stream>>>(x, tgt, cen, partial, B);
    tcl_reduce<<<1, 256, 0, stream>>>(partial, out, nblocks, 1.0f / (float)B);
}

// Round 6
// 18.169 us; speedup vs baseline: 1.6343x; 1.2040x over previous
//
#include <hip/hip_runtime.h>
#include <math.h>

// TripletCenterLoss, collapsed O(B^2) -> O(B*C):
//   dist_ap[i] = ||x_i - centers[t_i]||    (all same-class j share it; j=i exists)
//   dist_an[i] = min_{c present, c != t_i} ||x_i - centers[c]||
//   loss = mean(relu(MARGIN + dist_ap - dist_an))
// d2 via x2 + c2 - 2*x.c (reference's own expansion), dist = sqrt(clip(d2,1e-12)).
//
// Geometry: 512 blocks x 256 threads (2 blocks/CU, 2 waves/SIMD), 16 rows/block.
// Wave owns 4 rows; lane l owns classes {2l, 2l+1} (CPAD=112; lanes>=50 partly
// pad -> masked via present[] / target match). One center ds_read_b128 feeds 4
// rows' FMAs. x block (8KB) is ALSO staged to LDS (round-4 lesson: in-loop
// uniform global x loads = exposed cold-miss latency).
// Center LDS XOR-swizzled: byte(cl,d4) = cl*512 + ((d4 ^ ((cl>>1)&7))<<4);
// staged via global_load_lds with linear LDS dest + pre-swizzled global source
// (m173). Main-loop center reads are a conflict-free bank permutation; x reads
// are wave-uniform broadcasts.
// ROUND-5 BUG (fixed here): x2 phase must cover 16 rows x 32 chunks = 512
// chunks; previous version covered 128 chunks with an 8-chunk/row mapping.
// Now: 4 lanes/row x 8 chunks/lane, butterfly over lane^1,lane^2.
// NOTE (round-3 lesson): tiny hipMemsetAsync graph node ~ +11us; keep 2 kernels.

constexpr int T = 256;
constexpr int RPB = 16;        // rows per block
constexpr int RPW = 4;         // rows per wave
constexpr int CPAD = 112;      // padded classes (2 per lane for lanes 0..55)
constexpr int C = 100;
constexpr float MARGIN = 5.0f;

constexpr int CEN_CHUNKS = CPAD * 32;         // 3584 x 16B = 57344 B
constexpr int LDS_X_OFF  = CEN_CHUNKS * 16;   // 57344 (x block: 512 chunks, 8KB)
constexpr int LDS_C2     = 65536;             // float[128]
constexpr int LDS_X2     = 66048;             // float[16]
constexpr int LDS_PRES   = 66112;             // uchar[128]
constexpr int LDS_WRED   = 66240;             // float[4]
constexpr int LDS_TOTAL  = 66304;             // pad-lane garbage reads stay in-bounds

__device__ __forceinline__ float4 fma4(float4 a, float4 b, float4 c) {
    return make_float4(fmaf(a.x, b.x, c.x), fmaf(a.y, b.y, c.y),
                       fmaf(a.z, b.z, c.z), fmaf(a.w, b.w, c.w));
}
__device__ __forceinline__ float hsum4(float4 v) {
    return (v.x + v.y) + (v.z + v.w);
}

__global__ __launch_bounds__(256) void tcl_main(
    const float* __restrict__ x, const int* __restrict__ tgt,
    const float* __restrict__ cen, float* __restrict__ partial, int B)
{
    __shared__ __align__(16) char lds[LDS_TOTAL];
    float* c2s = (float*)(lds + LDS_C2);
    float* x2s = (float*)(lds + LDS_X2);
    unsigned char* present = (unsigned char*)(lds + LDS_PRES);
    float* wred = (float*)(lds + LDS_WRED);

    const int tid  = threadIdx.x;
    const int bid  = blockIdx.x;
    const int lane = tid & 63;
    const int wid  = __builtin_amdgcn_readfirstlane(tid >> 6);
    const float* xblk = x + (size_t)bid * RPB * 128;

    // ---- stage centers (swizzled) + x block (linear) : 4096 chunks, 16/thread ----
    #pragma unroll
    for (int k = 0; k < 16; ++k) {
        const int j = k * T + tid;               // linear dest chunk
        const char* src;
        if (k < 14) {                            // center chunks 0..3583
            const int cl  = j >> 5;
            const int scl = (cl < C) ? cl : 0;   // pads alias class 0 (masked)
            const int srcChunk = scl * 32 + ((j & 31) ^ ((scl >> 1) & 7));
            src = (const char*)cen + srcChunk * 16;
        } else {                                 // x chunks 0..511
            src = (const char*)xblk + (size_t)(j - CEN_CHUNKS) * 16;
        }
        __builtin_amdgcn_global_load_lds(
            (const __attribute__((address_space(1))) void*)src,
            (__attribute__((address_space(3))) void*)(lds + (size_t)(k * T + wid * 64) * 16),
            16, 0, 0);
    }

    // ---- overlapped with staging: presence (wave 2) and x2 (wave 3) ----
    if (wid == 2) {
        present[lane] = 0; present[64 + lane] = 0;    // wave-synchronous clear
        for (int it = 0; it < 32; ++it) {
            const int4 tv = reinterpret_cast<const int4*>(tgt)[it * 64 + lane];
            present[tv.x] = 1; present[tv.y] = 1;
            present[tv.z] = 1; present[tv.w] = 1;
        }
    } else if (wid == 3) {
        // 16 rows x 32 chunks = 512 chunks; 4 lanes/row, 8 chunks/lane.
        float4 acc = make_float4(0.f, 0.f, 0.f, 0.f);
        #pragma unroll
        for (int c = 0; c < 8; ++c) {
            const float4 v = reinterpret_cast<const float4*>(xblk)[lane * 8 + c];
            acc = fma4(v, v, acc);
        }
        float s = hsum4(acc);
        s += __shfl_xor(s, 1);
        s += __shfl_xor(s, 2);                        // 4 lanes per row
        if ((lane & 3) == 0) x2s[lane >> 2] = s;
    }
    __syncthreads();   // drains staging vmcnt + joins all waves

    // ---- c2 from staged LDS (waves 0-1), zero-fill pad slots ----
    if (tid < 128) {
        float val = 0.f;
        if (tid < CPAD) {
            const int vbb = tid * 512 + (((tid >> 1) & 7) << 4);
            float4 acc = make_float4(0.f, 0.f, 0.f, 0.f);
            #pragma unroll 8
            for (int e = 0; e < 32; ++e) {
                const float4 v = *reinterpret_cast<const float4*>(lds + (vbb ^ (e << 4)));
                acc = fma4(v, v, acc);
            }
            val = hsum4(acc);
        }
        c2s[tid] = val;
    }
    __syncthreads();

    // ---- main loop: 4 rows/wave, 2 classes/lane, all operands from LDS ----
    const char* xld = lds + LDS_X_OFF + wid * RPW * 512;   // wave's 4 rows
    const int vb = lane * 1024 + ((lane & 7) << 4);        // swizzled center base

    float4 a[RPW][2];
    #pragma unroll
    for (int r = 0; r < RPW; ++r) {
        a[r][0] = make_float4(0.f, 0.f, 0.f, 0.f);
        a[r][1] = make_float4(0.f, 0.f, 0.f, 0.f);
    }

    #pragma unroll 4
    for (int d4 = 0; d4 < 32; ++d4) {
        float4 xv[RPW];
        #pragma unroll
        for (int r = 0; r < RPW; ++r)   // wave-uniform address -> LDS broadcast
            xv[r] = *reinterpret_cast<const float4*>(xld + r * 512 + d4 * 16);
        const char* p = lds + (vb ^ (d4 << 4));
        const float4 cv0 = *reinterpret_cast<const float4*>(p);
        const float4 cv1 = *reinterpret_cast<const float4*>(p + 512);
        #pragma unroll
        for (int r = 0; r < RPW; ++r) {
            a[r][0] = fma4(xv[r], cv0, a[r][0]);
            a[r][1] = fma4(xv[r], cv1, a[r][1]);
        }
    }

    // ---- epilogue: d2, ap/an per row, 64-lane butterfly, per-wave term sum ----
    const int rowg = bid * RPB + wid * RPW;
    int tr[RPW]; float x2v[RPW];
    #pragma unroll
    for (int r = 0; r < RPW; ++r) {
        tr[r]  = tgt[rowg + r];                 // wave-uniform scalar loads, L2-hot
        x2v[r] = x2s[wid * RPW + r];
    }
    const int cl0 = 2 * lane, cl1 = 2 * lane + 1;
    const float c20 = c2s[cl0], c21 = c2s[cl1];
    const bool p0 = present[cl0] != 0, p1 = present[cl1] != 0;

    float term = 0.f;
    #pragma unroll
    for (int r = 0; r < RPW; ++r) {
        const float d20 = fmaxf(x2v[r] + c20 - 2.f * hsum4(a[r][0]), 1e-12f);
        const float d21 = fmaxf(x2v[r] + c21 - 2.f * hsum4(a[r][1]), 1e-12f);
        float ap = (cl0 == tr[r]) ? d20 : ((cl1 == tr[r]) ? d21 : -1.f);
        float an = fminf((p0 && cl0 != tr[r]) ? d20 : INFINITY,
                         (p1 && cl1 != tr[r]) ? d21 : INFINITY);
        #pragma unroll
        for (int off = 1; off < 64; off <<= 1) {
            ap = fmaxf(ap, __shfl_xor(ap, off));
            an = fminf(an, __shfl_xor(an, off));
        }
        term += fmaxf(0.f, MARGIN + sqrtf(ap) - sqrtf(an));
    }

    if (lane == 0) wred[wid] = term;
    __syncthreads();
    if (tid == 0) partial[bid] = (wred[0] + wred[1]) + (wred[2] + wred[3]);
}

__global__ __launch_bounds__(256) void tcl_reduce(
    const float* __restrict__ partial, float* __restrict__ out, float invB)
{
    __shared__ float wred[4];
    const int tid = threadIdx.x;
    float v = partial[tid] + partial[tid + 256];   // 512 partials
    #pragma unroll
    for (int off = 1; off < 64; off <<= 1) v += __shfl_xor(v, off);
    if ((tid & 63) == 0) wred[tid >> 6] = v;
    __syncthreads();
    if (tid == 0)
        out[0] = ((wred[0] + wred[1]) + (wred[2] + wred[3])) * invB;
}

extern "C" void kernel_launch(void* const* d_in, const int* in_sizes, int n_in,
                              void* d_out, int out_size, void* d_ws, size_t ws_size,
                              hipStream_t stream)
{
    const float* x   = (const float*)d_in[0];   // [B, 128] f32
    const int*   tgt = (const int*)d_in[1];     // [B] int32 (harness-converted)
    const float* cen = (const float*)d_in[2];   // [100, 128] f32
    float* out = (float*)d_out;                 // scalar f32
    float* partial = (float*)d_ws;

    const int B = in_sizes[1];                  // 8192
    const int nblocks = B / RPB;                // 512

    tcl_main<<<nblocks, T, 0, stream>>>(x, tgt, cen, partial, B);
    tcl_reduce<<<1, 256, 0, stream>>>(partial, out, 1.0f / (float)B);
}